// Round 15
// baseline (127.550 us; speedup 1.0000x reference)
//
#include <hip/hip_runtime.h>

// ---------------- types ----------------
typedef __bf16 bf16;
typedef __bf16 bf16x2 __attribute__((ext_vector_type(2)));
typedef __bf16 bf16x8 __attribute__((ext_vector_type(8)));
typedef float  f32x4  __attribute__((ext_vector_type(4)));
typedef float  f32x16 __attribute__((ext_vector_type(16)));
typedef unsigned int u32;
typedef unsigned int u32x4 __attribute__((ext_vector_type(4)));

typedef __attribute__((address_space(1))) unsigned int gu32;
typedef __attribute__((address_space(3))) unsigned int lu32;

// async global->LDS, 16B per lane; LDS dest = wave-uniform base + lane*16
__device__ __forceinline__ void llds16(const void* g, void* l) {
  __builtin_amdgcn_global_load_lds((gu32*)g, (lu32*)l, 16, 0, 0);
}

// ---------------- fp32 -> bf16 converts (vectorized, 8 elems/thread) -------
__device__ __forceinline__ void cvt8(const float* __restrict__ src,
                                     bf16* __restrict__ dst, int i) {
  const float4* s4 = (const float4*)src;
  float4 a = s4[i * 2 + 0];
  float4 c = s4[i * 2 + 1];
  bf16x8 o;
  o[0] = (bf16)a.x; o[1] = (bf16)a.y; o[2] = (bf16)a.z; o[3] = (bf16)a.w;
  o[4] = (bf16)c.x; o[5] = (bf16)c.y; o[6] = (bf16)c.z; o[7] = (bf16)c.w;
  ((bf16x8*)dst)[i] = o;
}

__global__ __launch_bounds__(256) void cvt_bf16(const float* __restrict__ src,
                                                bf16* __restrict__ dst, int n8) {
  int i = blockIdx.x * blockDim.x + threadIdx.x;
  if (i < n8) cvt8(src, dst, i);
}

// ONE launch for all 7 fp32->bf16 conversions
__global__ __launch_bounds__(256) void cvt_all(const float* __restrict__ w0,
                                               const float* __restrict__ w1,
                                               const float* __restrict__ w2,
                                               const float* __restrict__ w3,
                                               const float* __restrict__ x0,
                                               const float* __restrict__ x1,
                                               const float* __restrict__ x2,
                                               bf16* __restrict__ wdst,
                                               bf16* __restrict__ xdst) {
  const int b = blockIdx.x;
  if (b < 2048) {
    const int which = b >> 9;
    const float* src = (which == 0) ? w0 : (which == 1) ? w1 : (which == 2) ? w2 : w3;
    const int i = (b & 511) * 256 + threadIdx.x;
    cvt8(src, wdst + (size_t)which * (1u << 20), i);
  } else {
    const int b2 = b - 2048;
    const int which = b2 >> 11;
    const float* src = (which == 0) ? x0 : (which == 1) ? x1 : x2;
    const int i = (b2 & 2047) * 256 + threadIdx.x;
    cvt8(src, xdst + (size_t)which * (4u << 20), i);
  }
}

// ---------------- QKV projection GEMM (bf16 A via global_load_lds) ---------
// z = blockIdx.z + zoff -> (q,k,v). 128x128 tile, BK=32, 4 waves of 64x64.
// z<2: C -> bf16 [B,H,M,D]; z==2: [B,H,D,M]. z==0 pre-scaled by 0.125*log2e.
__global__ __launch_bounds__(256) void gemm_qkv(const bf16* __restrict__ A0,
                                                const bf16* __restrict__ A1,
                                                const bf16* __restrict__ A2,
                                                const bf16* __restrict__ Wb,
                                                bf16* __restrict__ qb,
                                                bf16* __restrict__ kb,
                                                bf16* __restrict__ vb,
                                                int zoff) {
  constexpr int K = 1024, BM = 128, BN = 128, BK = 32, NT = K / BK;
  __shared__ bf16 Alds[2][BM * BK];
  __shared__ bf16 Blds[2][BN * BK];
  const int t = threadIdx.x, w = t >> 6, l = t & 63;
  const int lr = l & 15, lg = l >> 4;
  const int bm = blockIdx.x * BM, bn = blockIdx.y * BN;
  const int z = blockIdx.z + zoff;
  const bf16* A = (z == 0) ? A0 : (z == 1) ? A1 : A2;
  const bf16* W = Wb + (size_t)z * (1u << 20);
  const int wm = (w >> 1) * 64, wn = (w & 1) * 64;

  f32x4 acc[4][4] = {};

  auto stage = [&](int buf, int kt) {
    const int k0 = kt * BK;
#pragma unroll
    for (int i = 0; i < 2; ++i) {
      int idx = i * 256 + t;
      int row = idx >> 2, kb2 = (idx & 3) * 16;
      llds16((const char*)A + ((size_t)(bm + row) * K + k0) * 2 + kb2,
             (char*)(&Alds[buf][0]) + (i * 4 + w) * 1024);
    }
#pragma unroll
    for (int i = 0; i < 2; ++i) {
      int idx = i * 256 + t;
      int row = idx >> 2, kb2 = (idx & 3) * 16;
      llds16((const char*)W + ((size_t)(bn + row) * K + k0) * 2 + kb2,
             (char*)(&Blds[buf][0]) + (i * 4 + w) * 1024);
    }
  };

  stage(0, 0);
  for (int kt = 0; kt < NT; ++kt) {
    __syncthreads();
    if (kt + 1 < NT) stage((kt + 1) & 1, kt + 1);
    const int cur = kt & 1;
    bf16x8 af[4], bfr[4];
#pragma unroll
    for (int i = 0; i < 4; ++i)
      af[i] = *(const bf16x8*)(&Alds[cur][(wm + i * 16 + lr) * BK + lg * 8]);
#pragma unroll
    for (int j = 0; j < 4; ++j)
      bfr[j] = *(const bf16x8*)(&Blds[cur][(wn + j * 16 + lr) * BK + lg * 8]);
    __builtin_amdgcn_s_setprio(1);
#pragma unroll
    for (int i = 0; i < 4; ++i)
#pragma unroll
      for (int j = 0; j < 4; ++j)
        acc[i][j] = __builtin_amdgcn_mfma_f32_16x16x32_bf16(af[i], bfr[j], acc[i][j], 0, 0, 0);
    __builtin_amdgcn_s_setprio(0);
  }

  bf16* Cout = (z == 0) ? qb : (z == 1) ? kb : vb;
  const float osc = (z == 0) ? 0.1803368801f : 1.0f;   // 0.125 * log2(e)
#pragma unroll
  for (int i = 0; i < 4; ++i) {
#pragma unroll
    for (int j = 0; j < 4; ++j) {
#pragma unroll
      for (int r = 0; r < 4; ++r) {
        const int gm = bm + wm + i * 16 + lg * 4 + r;
        const int n  = bn + wn + j * 16 + lr;
        const int b = gm >> 11, m = gm & 2047;
        const int h = n >> 6, d = n & 63;
        const size_t off = (z < 2)
            ? ((size_t)((b * 16 + h) * 2048 + m) * 64 + d)
            : ((size_t)((b * 16 + h) * 64 + d) * 2048 + m);
        Cout[off] = (bf16)(acc[i][j][r] * osc);
      }
    }
  }
}

// ---------------- output GEMM: C = A(MxK).B(NxK)^T -> f32 [M,N] ------------
// 128x64 tile, grid (32,16) = 512 blocks (proven config).
__global__ __launch_bounds__(256) void gemm_out(const bf16* __restrict__ A,
                                                const bf16* __restrict__ Bw,
                                                float* __restrict__ Cout) {
  constexpr int N = 1024, K = 1024;
  constexpr int BM = 128, BN = 64, BK = 32;
  __shared__ bf16 Alds[2][BM * BK];
  __shared__ bf16 Blds[2][BN * BK];
  const int t = threadIdx.x;
  const int w = t >> 6, l = t & 63;
  const int lr = l & 15, lg = l >> 4;
  const int bm = blockIdx.x * BM, bn = blockIdx.y * BN;
  const int wm = (w >> 1) * 64, wn = (w & 1) * 32;

  f32x4 acc[4][2] = {};

  auto stage = [&](int buf, int kt) {
    const int k0 = kt * BK;
#pragma unroll
    for (int i = 0; i < 2; ++i) {
      int idx = i * 256 + t;
      int row = idx >> 2, kb = (idx & 3) * 16;
      const char* g = (const char*)A + ((size_t)(bm + row) * K + k0) * 2 + kb;
      llds16(g, (char*)(&Alds[buf][0]) + (i * 4 + w) * 1024);
    }
    {
      int row = t >> 2, kb = (t & 3) * 16;
      const char* g = (const char*)Bw + ((size_t)(bn + row) * K + k0) * 2 + kb;
      llds16(g, (char*)(&Blds[buf][0]) + w * 1024);
    }
  };

  stage(0, 0);
  constexpr int NT = K / BK;
  for (int kt = 0; kt < NT; ++kt) {
    __syncthreads();
    if (kt + 1 < NT) stage((kt + 1) & 1, kt + 1);
    const int cur = kt & 1;
    bf16x8 af[4], bfr[2];
#pragma unroll
    for (int i = 0; i < 4; ++i)
      af[i] = *(const bf16x8*)(&Alds[cur][(wm + i * 16 + lr) * BK + lg * 8]);
#pragma unroll
    for (int j = 0; j < 2; ++j)
      bfr[j] = *(const bf16x8*)(&Blds[cur][(wn + j * 16 + lr) * BK + lg * 8]);
    __builtin_amdgcn_s_setprio(1);
#pragma unroll
    for (int i = 0; i < 4; ++i)
#pragma unroll
      for (int j = 0; j < 2; ++j)
        acc[i][j] = __builtin_amdgcn_mfma_f32_16x16x32_bf16(af[i], bfr[j], acc[i][j], 0, 0, 0);
    __builtin_amdgcn_s_setprio(0);
  }

#pragma unroll
  for (int i = 0; i < 4; ++i)
#pragma unroll
    for (int j = 0; j < 2; ++j)
#pragma unroll
      for (int r = 0; r < 4; ++r) {
        const int gm = bm + wm + i * 16 + lg * 4 + r;
        const int n  = bn + wn + j * 16 + lr;
        Cout[(size_t)gm * N + n] = acc[i][j][r];
      }
}

// ---------------- flash attention: rotated pipeline, PV in the stall window
// r14 base (4 waves x 32q, K+V in LDS 4-buf, counted vmcnt, XCD swizzle,
// MFMA-ones denominator, QK(t)->PV(t-1)->EXP(t) rotation). NEW: PV(t-1) is
// issued BEFORE the vmcnt+barrier -- it depends only on buf (t-1)&3 (resident
// since barrier t-1) and on EXP(t-1)'s registers, so its 12 matrix ops fill
// the stage-retire + barrier-convergence window where waves previously
// idled. Single P-word buffer suffices (PV reads old words, EXP writes new
// ones after it). WAR: stage(t+1) writes (t+1)&3, PV reads (t-1)&3 --
// distance 2 < 4 bufs; barriers order all cross-iteration reuse.
__global__ __launch_bounds__(256) void attn_fwd(const bf16* __restrict__ Qb,
                                                const bf16* __restrict__ Kb,
                                                const bf16* __restrict__ Vt,
                                                bf16* __restrict__ Out) {
  constexpr int Mlen = 2048, KVB = 64, NTT = Mlen / KVB;
  __shared__ bf16 Klds[4][KVB * 64];   // [kv][d] 128B rows, swizzled (32KB)
  __shared__ bf16 Vlds[4][64 * KVB];   // [d][kv] 128B rows, swizzled (32KB)
  const int t = threadIdx.x, w = t >> 6, l = t & 63;
  const int l31 = l & 31, hi = l >> 5;
  const int orig = blockIdx.x;
  const int wg = (orig & 7) * 64 + (orig >> 3);   // XCD bijective swizzle
  const int bh = wg >> 4;
  const int qr = (wg & 15) * 128 + w * 32;
  const int key = (l31 & 7) << 4;

  const bf16* qbase = Qb + ((size_t)bh * Mlen + qr + l31) * 64;
  bf16x8 qf[4];
#pragma unroll
  for (int dks = 0; dks < 4; ++dks)
    qf[dks] = *(const bf16x8*)(qbase + dks * 16 + hi * 8);

  u32x4 onesw;
  onesw[0] = 0x3F803F80u; onesw[1] = 0x3F803F80u;
  onesw[2] = 0x3F803F80u; onesw[3] = 0x3F803F80u;
  const bf16x8 ones = __builtin_bit_cast(bf16x8, onesw);

  f32x16 acco0 = {}, acco1 = {};
  f32x16 accl = {};

  const char* kTile0 = (const char*)Kb + (size_t)bh * Mlen * 64 * 2;
  const char* vBase  = (const char*)Vt + (size_t)bh * 64 * Mlen * 2;

  auto stageKV = [&](int buf, int tile) {
    const int kv0 = tile * KVB;
#pragma unroll
    for (int i = 0; i < 2; ++i) {
      int idx = i * 256 + t;
      int L = idx * 16;
      int row = L >> 7;
      int inner = (L & 127) ^ ((row & 7) << 4);
      llds16(kTile0 + (size_t)(kv0 + row) * 128 + inner,
             (char*)(&Klds[buf][0]) + (i * 4 + w) * 1024);
    }
#pragma unroll
    for (int i = 0; i < 2; ++i) {
      int idx = i * 256 + t;
      int L = idx * 16;
      int d = L >> 7;
      int inner = (L & 127) ^ ((d & 7) << 4);
      llds16(vBase + (size_t)d * (Mlen * 2) + kv0 * 2 + inner,
             (char*)(&Vlds[buf][0]) + (i * 4 + w) * 1024);
    }
  };

  auto QK = [&](int tile, f32x16& s0, f32x16& s1) {
    const char* kb_ = (const char*)(&Klds[tile & 3][0]);
    __builtin_amdgcn_s_setprio(1);
#pragma unroll
    for (int dks = 0; dks < 4; ++dks) {
      const int a0 = (0 * 32 + l31) * 128 + ((dks * 32 + hi * 16) ^ key);
      const int a1 = (1 * 32 + l31) * 128 + ((dks * 32 + hi * 16) ^ key);
      bf16x8 kf0 = *(const bf16x8*)(kb_ + a0);
      bf16x8 kf1 = *(const bf16x8*)(kb_ + a1);
      s0 = __builtin_amdgcn_mfma_f32_32x32x16_bf16(kf0, qf[dks], s0, 0, 0, 0);
      s1 = __builtin_amdgcn_mfma_f32_32x32x16_bf16(kf1, qf[dks], s1, 0, 0, 0);
    }
    __builtin_amdgcn_s_setprio(0);
  };
  auto EXP = [&](const f32x16& s0, const f32x16& s1, u32 (&w0)[8], u32 (&w1)[8]) {
#pragma unroll
    for (int e2 = 0; e2 < 8; ++e2) {
      const float p00 = __builtin_amdgcn_exp2f(s0[2 * e2]);
      const float p01 = __builtin_amdgcn_exp2f(s0[2 * e2 + 1]);
      const float p10 = __builtin_amdgcn_exp2f(s1[2 * e2]);
      const float p11 = __builtin_amdgcn_exp2f(s1[2 * e2 + 1]);
      bf16x2 k0; k0[0] = (bf16)p00; k0[1] = (bf16)p01;
      bf16x2 k1; k1[0] = (bf16)p10; k1[1] = (bf16)p11;
      w0[e2] = __builtin_bit_cast(u32, k0);
      w1[e2] = __builtin_bit_cast(u32, k1);
    }
  };
  auto PV = [&](int tprev, const u32 (&w0)[8], const u32 (&w1)[8]) {
    const char* vb_ = (const char*)(&Vlds[tprev & 3][0]);
    __builtin_amdgcn_s_setprio(1);
#pragma unroll
    for (int ks = 0; ks < 2; ++ks) {
      auto sa0 = __builtin_amdgcn_permlane32_swap(w0[4 * ks + 0], w0[4 * ks + 2], false, false);
      auto sa1 = __builtin_amdgcn_permlane32_swap(w0[4 * ks + 1], w0[4 * ks + 3], false, false);
      auto sb0 = __builtin_amdgcn_permlane32_swap(w1[4 * ks + 0], w1[4 * ks + 2], false, false);
      auto sb1 = __builtin_amdgcn_permlane32_swap(w1[4 * ks + 1], w1[4 * ks + 3], false, false);
      u32x4 fa, fb;
      fa[0] = (u32)sa0[0]; fa[1] = (u32)sa1[0]; fa[2] = (u32)sa0[1]; fa[3] = (u32)sa1[1];
      fb[0] = (u32)sb0[0]; fb[1] = (u32)sb1[0]; fb[2] = (u32)sb0[1]; fb[3] = (u32)sb1[1];
      const bf16x8 pa = __builtin_bit_cast(bf16x8, fa);
      const bf16x8 pb = __builtin_bit_cast(bf16x8, fb);
      const int c0 = (ks * 32 + hi * 16);
      bf16x8 va0 = *(const bf16x8*)(vb_ + (0 * 32 + l31) * 128 + ((0 * 64 + c0) ^ key));
      bf16x8 va1 = *(const bf16x8*)(vb_ + (1 * 32 + l31) * 128 + ((0 * 64 + c0) ^ key));
      bf16x8 vb0 = *(const bf16x8*)(vb_ + (0 * 32 + l31) * 128 + ((1 * 64 + c0) ^ key));
      bf16x8 vb1 = *(const bf16x8*)(vb_ + (1 * 32 + l31) * 128 + ((1 * 64 + c0) ^ key));
      acco0 = __builtin_amdgcn_mfma_f32_32x32x16_bf16(pa, va0, acco0, 0, 0, 0);
      acco1 = __builtin_amdgcn_mfma_f32_32x32x16_bf16(pa, va1, acco1, 0, 0, 0);
      accl  = __builtin_amdgcn_mfma_f32_32x32x16_bf16(pa, ones, accl, 0, 0, 0);
      acco0 = __builtin_amdgcn_mfma_f32_32x32x16_bf16(pb, vb0, acco0, 0, 0, 0);
      acco1 = __builtin_amdgcn_mfma_f32_32x32x16_bf16(pb, vb1, acco1, 0, 0, 0);
      accl  = __builtin_amdgcn_mfma_f32_32x32x16_bf16(pb, ones, accl, 0, 0, 0);
    }
    __builtin_amdgcn_s_setprio(0);
  };

  u32 w0[8], w1[8];
  f32x16 s0, s1;

  stageKV(0, 0);
  // tile 0: no PV yet
  stageKV(1, 1);
  asm volatile("s_waitcnt vmcnt(4)" ::: "memory");
  __builtin_amdgcn_s_barrier();
  __builtin_amdgcn_sched_barrier(0);
  s0 = f32x16{}; s1 = f32x16{};
  QK(0, s0, s1);
  EXP(s0, s1, w0, w1);

  // tiles 1..30: {stage(t+1); PV(t-1); vmcnt(4); barrier; QK(t); EXP(t)}
  for (int tile = 1; tile < NTT - 1; ++tile) {
    stageKV((tile + 1) & 3, tile + 1);
    PV(tile - 1, w0, w1);
    asm volatile("s_waitcnt vmcnt(4)" ::: "memory");
    __builtin_amdgcn_s_barrier();
    __builtin_amdgcn_sched_barrier(0);
    s0 = f32x16{}; s1 = f32x16{};
    QK(tile, s0, s1);
    EXP(s0, s1, w0, w1);
  }

  // tile 31: no stage; drain
  PV(30, w0, w1);
  asm volatile("s_waitcnt vmcnt(0)" ::: "memory");
  __builtin_amdgcn_s_barrier();
  __builtin_amdgcn_sched_barrier(0);
  s0 = f32x16{}; s1 = f32x16{};
  QK(31, s0, s1);
  EXP(s0, s1, w0, w1);
  PV(31, w0, w1);

  // epilogue: per-element divide; accl[e] is the denominator for acco*[e]'s q
  const int b = bh >> 4, h = bh & 15;
#pragma unroll
  for (int e = 0; e < 16; ++e) {
    const int ql = (e & 3) + 8 * (e >> 2) + 4 * hi;
    const float iv = 1.0f / accl[e];
    const size_t row = (size_t)(b * 2048 + qr + ql) * 1024 + h * 64;
    Out[row + l31]      = (bf16)(acco0[e] * iv);
    Out[row + 32 + l31] = (bf16)(acco1[e] * iv);
  }
}

// ---------------- launch ----------------
extern "C" void kernel_launch(void* const* d_in, const int* in_sizes, int n_in,
                              void* d_out, int out_size, void* d_ws, size_t ws_size,
                              hipStream_t stream) {
  const float* q  = (const float*)d_in[0];
  const float* k  = (const float*)d_in[1];
  const float* v  = (const float*)d_in[2];
  const float* Wq = (const float*)d_in[3];
  const float* Wk = (const float*)d_in[4];
  const float* Wv = (const float*)d_in[5];
  const float* Wo = (const float*)d_in[6];

  char* ws = (char*)d_ws;
  const dim3 cb(256);

  if (ws_size >= ((size_t)56 << 20)) {
    // Wb@0(8M); Xq/Xk/Xv@8/16/24; qb/kb/vb@32/40/48; Xa@8 (reuse Xq)
    bf16* Wb = (bf16*)ws;
    bf16* Xq = (bf16*)(ws + (8u  << 20));
    bf16* Xk = (bf16*)(ws + (16u << 20));
    bf16* Xv = (bf16*)(ws + (24u << 20));
    bf16* qb = (bf16*)(ws + (32u << 20));
    bf16* kb = (bf16*)(ws + (40u << 20));
    bf16* vb = (bf16*)(ws + (48u << 20));
    bf16* Xa = (bf16*)(ws + (8u  << 20));

    cvt_all<<<8192, cb, 0, stream>>>(Wq, Wk, Wv, Wo, q, k, v, Wb, Xq);
    gemm_qkv<<<dim3(32, 8, 3), cb, 0, stream>>>(Xq, Xk, Xv, Wb, qb, kb, vb, 0);
    attn_fwd<<<512, cb, 0, stream>>>(qb, kb, vb, Xa);
    gemm_out<<<dim3(32, 16), cb, 0, stream>>>(Xa, Wb + 3 * (1u << 20), (float*)d_out);
  } else {
    // serial fallback (40MB): Wb@0, X@8 (shared), qb@16, kb@24, vb@32, Xa@8
    bf16* Wb = (bf16*)ws;
    bf16* X  = (bf16*)(ws + (8u  << 20));
    bf16* qb = (bf16*)(ws + (16u << 20));
    bf16* kb = (bf16*)(ws + (24u << 20));
    bf16* vb = (bf16*)(ws + (32u << 20));
    bf16* Xa = (bf16*)(ws + (8u  << 20));

    cvt_all<<<2048, cb, 0, stream>>>(Wq, Wk, Wv, Wo, q, k, v, Wb, Wb); // weights only
    cvt_bf16<<<2048, cb, 0, stream>>>(q, X, 524288);
    gemm_qkv<<<dim3(32, 8, 1), cb, 0, stream>>>(X, X, X, Wb, qb, kb, vb, 0);
    cvt_bf16<<<2048, cb, 0, stream>>>(k, X, 524288);
    gemm_qkv<<<dim3(32, 8, 1), cb, 0, stream>>>(X, X, X, Wb, qb, kb, vb, 1);
    cvt_bf16<<<2048, cb, 0, stream>>>(v, X, 524288);
    gemm_qkv<<<dim3(32, 8, 1), cb, 0, stream>>>(X, X, X, Wb, qb, kb, vb, 2);
    attn_fwd<<<512, cb, 0, stream>>>(qb, kb, vb, Xa);
    gemm_out<<<dim3(32, 16), cb, 0, stream>>>(Xa, Wb + 3 * (1u << 20), (float*)d_out);
  }
}

// Round 16
// 120.946 us; speedup vs baseline: 1.0546x; 1.0546x over previous
//
#include <hip/hip_runtime.h>

// ---------------- types ----------------
typedef __bf16 bf16;
typedef __bf16 bf16x2 __attribute__((ext_vector_type(2)));
typedef __bf16 bf16x8 __attribute__((ext_vector_type(8)));
typedef float  f32x4  __attribute__((ext_vector_type(4)));
typedef float  f32x16 __attribute__((ext_vector_type(16)));
typedef unsigned int u32;
typedef unsigned int u32x4 __attribute__((ext_vector_type(4)));

typedef __attribute__((address_space(1))) unsigned int gu32;
typedef __attribute__((address_space(3))) unsigned int lu32;

// async global->LDS, 16B per lane; LDS dest = wave-uniform base + lane*16
__device__ __forceinline__ void llds16(const void* g, void* l) {
  __builtin_amdgcn_global_load_lds((gu32*)g, (lu32*)l, 16, 0, 0);
}

// ---------------- fp32 -> bf16 converts (vectorized, 8 elems/thread) -------
__device__ __forceinline__ void cvt8(const float* __restrict__ src,
                                     bf16* __restrict__ dst, int i) {
  const float4* s4 = (const float4*)src;
  float4 a = s4[i * 2 + 0];
  float4 c = s4[i * 2 + 1];
  bf16x8 o;
  o[0] = (bf16)a.x; o[1] = (bf16)a.y; o[2] = (bf16)a.z; o[3] = (bf16)a.w;
  o[4] = (bf16)c.x; o[5] = (bf16)c.y; o[6] = (bf16)c.z; o[7] = (bf16)c.w;
  ((bf16x8*)dst)[i] = o;
}

__global__ __launch_bounds__(256) void cvt_bf16(const float* __restrict__ src,
                                                bf16* __restrict__ dst, int n8) {
  int i = blockIdx.x * blockDim.x + threadIdx.x;
  if (i < n8) cvt8(src, dst, i);
}

// ONE launch for all 7 fp32->bf16 conversions
__global__ __launch_bounds__(256) void cvt_all(const float* __restrict__ w0,
                                               const float* __restrict__ w1,
                                               const float* __restrict__ w2,
                                               const float* __restrict__ w3,
                                               const float* __restrict__ x0,
                                               const float* __restrict__ x1,
                                               const float* __restrict__ x2,
                                               bf16* __restrict__ wdst,
                                               bf16* __restrict__ xdst) {
  const int b = blockIdx.x;
  if (b < 2048) {
    const int which = b >> 9;
    const float* src = (which == 0) ? w0 : (which == 1) ? w1 : (which == 2) ? w2 : w3;
    const int i = (b & 511) * 256 + threadIdx.x;
    cvt8(src, wdst + (size_t)which * (1u << 20), i);
  } else {
    const int b2 = b - 2048;
    const int which = b2 >> 11;
    const float* src = (which == 0) ? x0 : (which == 1) ? x1 : x2;
    const int i = (b2 & 2047) * 256 + threadIdx.x;
    cvt8(src, xdst + (size_t)which * (4u << 20), i);
  }
}

// ---------------- QKV projection GEMM (bf16 A via global_load_lds) ---------
// z = blockIdx.z + zoff -> (q,k,v). 128x128 tile, BK=32, 4 waves of 64x64.
// z<2: C -> bf16 [B,H,M,D]; z==2: [B,H,D,M]. z==0 pre-scaled by 0.125*log2e.
__global__ __launch_bounds__(256) void gemm_qkv(const bf16* __restrict__ A0,
                                                const bf16* __restrict__ A1,
                                                const bf16* __restrict__ A2,
                                                const bf16* __restrict__ Wb,
                                                bf16* __restrict__ qb,
                                                bf16* __restrict__ kb,
                                                bf16* __restrict__ vb,
                                                int zoff) {
  constexpr int K = 1024, BM = 128, BN = 128, BK = 32, NT = K / BK;
  __shared__ bf16 Alds[2][BM * BK];
  __shared__ bf16 Blds[2][BN * BK];
  const int t = threadIdx.x, w = t >> 6, l = t & 63;
  const int lr = l & 15, lg = l >> 4;
  const int bm = blockIdx.x * BM, bn = blockIdx.y * BN;
  const int z = blockIdx.z + zoff;
  const bf16* A = (z == 0) ? A0 : (z == 1) ? A1 : A2;
  const bf16* W = Wb + (size_t)z * (1u << 20);
  const int wm = (w >> 1) * 64, wn = (w & 1) * 64;

  f32x4 acc[4][4] = {};

  auto stage = [&](int buf, int kt) {
    const int k0 = kt * BK;
#pragma unroll
    for (int i = 0; i < 2; ++i) {
      int idx = i * 256 + t;
      int row = idx >> 2, kb2 = (idx & 3) * 16;
      llds16((const char*)A + ((size_t)(bm + row) * K + k0) * 2 + kb2,
             (char*)(&Alds[buf][0]) + (i * 4 + w) * 1024);
    }
#pragma unroll
    for (int i = 0; i < 2; ++i) {
      int idx = i * 256 + t;
      int row = idx >> 2, kb2 = (idx & 3) * 16;
      llds16((const char*)W + ((size_t)(bn + row) * K + k0) * 2 + kb2,
             (char*)(&Blds[buf][0]) + (i * 4 + w) * 1024);
    }
  };

  stage(0, 0);
  for (int kt = 0; kt < NT; ++kt) {
    __syncthreads();
    if (kt + 1 < NT) stage((kt + 1) & 1, kt + 1);
    const int cur = kt & 1;
    bf16x8 af[4], bfr[4];
#pragma unroll
    for (int i = 0; i < 4; ++i)
      af[i] = *(const bf16x8*)(&Alds[cur][(wm + i * 16 + lr) * BK + lg * 8]);
#pragma unroll
    for (int j = 0; j < 4; ++j)
      bfr[j] = *(const bf16x8*)(&Blds[cur][(wn + j * 16 + lr) * BK + lg * 8]);
    __builtin_amdgcn_s_setprio(1);
#pragma unroll
    for (int i = 0; i < 4; ++i)
#pragma unroll
      for (int j = 0; j < 4; ++j)
        acc[i][j] = __builtin_amdgcn_mfma_f32_16x16x32_bf16(af[i], bfr[j], acc[i][j], 0, 0, 0);
    __builtin_amdgcn_s_setprio(0);
  }

  bf16* Cout = (z == 0) ? qb : (z == 1) ? kb : vb;
  const float osc = (z == 0) ? 0.1803368801f : 1.0f;   // 0.125 * log2(e)
#pragma unroll
  for (int i = 0; i < 4; ++i) {
#pragma unroll
    for (int j = 0; j < 4; ++j) {
#pragma unroll
      for (int r = 0; r < 4; ++r) {
        const int gm = bm + wm + i * 16 + lg * 4 + r;
        const int n  = bn + wn + j * 16 + lr;
        const int b = gm >> 11, m = gm & 2047;
        const int h = n >> 6, d = n & 63;
        const size_t off = (z < 2)
            ? ((size_t)((b * 16 + h) * 2048 + m) * 64 + d)
            : ((size_t)((b * 16 + h) * 64 + d) * 2048 + m);
        Cout[off] = (bf16)(acc[i][j][r] * osc);
      }
    }
  }
}

// ---------------- output GEMM: C = A(MxK).B(NxK)^T -> f32 [M,N] ------------
// 128x64 tile, BK=64 (16 MFMA per barrier, 16 K-iters). 128B LDS rows are
// XOR-swizzled per rule #21: llds16 linear dest + global source chunk
// c^(row&7); fragment reads XOR (lr&7)<<4. Grid (32,16) = 512 blocks.
__global__ __launch_bounds__(256) void gemm_out(const bf16* __restrict__ A,
                                                const bf16* __restrict__ Bw,
                                                float* __restrict__ Cout) {
  constexpr int N = 1024, K = 1024;
  constexpr int BM = 128, BN = 64, BK = 64, NT = K / BK;
  __shared__ bf16 Alds[2][BM * BK];   // 16KB per buf
  __shared__ bf16 Blds[2][BN * BK];   // 8KB per buf
  const int t = threadIdx.x;
  const int w = t >> 6, l = t & 63;
  const int lr = l & 15, lg = l >> 4;
  const int bm = blockIdx.x * BM, bn = blockIdx.y * BN;
  const int wm = (w >> 1) * 64, wn = (w & 1) * 32;
  const int key = (lr & 7) << 4;       // read-side swizzle key

  f32x4 acc[4][2] = {};

  auto stage = [&](int buf, int kt) {
    const int k0 = kt * BK;
    // A: 128 rows x 8 chunks of 16B; LDS linear, source chunk pre-swizzled
#pragma unroll
    for (int i = 0; i < 4; ++i) {
      int idx = i * 256 + t;
      int row = idx >> 3, c = idx & 7;
      llds16((const char*)A + ((size_t)(bm + row) * K + k0) * 2 + ((c ^ (row & 7)) * 16),
             (char*)(&Alds[buf][0]) + (i * 4 + w) * 1024);
    }
    // B: 64 rows x 8 chunks
#pragma unroll
    for (int i = 0; i < 2; ++i) {
      int idx = i * 256 + t;
      int row = idx >> 3, c = idx & 7;
      llds16((const char*)Bw + ((size_t)(bn + row) * K + k0) * 2 + ((c ^ (row & 7)) * 16),
             (char*)(&Blds[buf][0]) + (i * 4 + w) * 1024);
    }
  };

  stage(0, 0);
  for (int kt = 0; kt < NT; ++kt) {
    __syncthreads();
    if (kt + 1 < NT) stage((kt + 1) & 1, kt + 1);
    const int cur = kt & 1;
    bf16x8 af[4][2], bfr[2][2];
#pragma unroll
    for (int i = 0; i < 4; ++i) {
      const int row = wm + i * 16 + lr;          // row&7 == lr&7
      const char* rb = (const char*)(&Alds[cur][0]) + row * 128;
#pragma unroll
      for (int kk = 0; kk < 2; ++kk)
        af[i][kk] = *(const bf16x8*)(rb + ((kk * 64 + lg * 16) ^ key));
    }
#pragma unroll
    for (int j = 0; j < 2; ++j) {
      const int row = wn + j * 16 + lr;
      const char* rb = (const char*)(&Blds[cur][0]) + row * 128;
#pragma unroll
      for (int kk = 0; kk < 2; ++kk)
        bfr[j][kk] = *(const bf16x8*)(rb + ((kk * 64 + lg * 16) ^ key));
    }
    __builtin_amdgcn_s_setprio(1);
#pragma unroll
    for (int kk = 0; kk < 2; ++kk)
#pragma unroll
      for (int i = 0; i < 4; ++i)
#pragma unroll
        for (int j = 0; j < 2; ++j)
          acc[i][j] = __builtin_amdgcn_mfma_f32_16x16x32_bf16(af[i][kk], bfr[j][kk], acc[i][j], 0, 0, 0);
    __builtin_amdgcn_s_setprio(0);
  }

#pragma unroll
  for (int i = 0; i < 4; ++i)
#pragma unroll
    for (int j = 0; j < 2; ++j)
#pragma unroll
      for (int r = 0; r < 4; ++r) {
        const int gm = bm + wm + i * 16 + lg * 4 + r;
        const int n  = bn + wn + j * 16 + lr;
        Cout[(size_t)gm * N + n] = acc[i][j][r];
      }
}

// ---------------- flash attention: rotated software pipeline (r14 exact) ---
// 4 waves x 32q, K+V in LDS 4-buf, counted vmcnt, XCD swizzle, MFMA-ones
// denominator, rotation QK(t) -> PV(t-1) -> EXP(t) with wE/wO double-buffered
// P words. Proven 49.1us.
__global__ __launch_bounds__(256) void attn_fwd(const bf16* __restrict__ Qb,
                                                const bf16* __restrict__ Kb,
                                                const bf16* __restrict__ Vt,
                                                bf16* __restrict__ Out) {
  constexpr int Mlen = 2048, KVB = 64, NTT = Mlen / KVB;
  __shared__ bf16 Klds[4][KVB * 64];   // [kv][d] 128B rows, swizzled (32KB)
  __shared__ bf16 Vlds[4][64 * KVB];   // [d][kv] 128B rows, swizzled (32KB)
  const int t = threadIdx.x, w = t >> 6, l = t & 63;
  const int l31 = l & 31, hi = l >> 5;
  const int orig = blockIdx.x;
  const int wg = (orig & 7) * 64 + (orig >> 3);   // XCD bijective swizzle
  const int bh = wg >> 4;
  const int qr = (wg & 15) * 128 + w * 32;
  const int key = (l31 & 7) << 4;

  const bf16* qbase = Qb + ((size_t)bh * Mlen + qr + l31) * 64;
  bf16x8 qf[4];
#pragma unroll
  for (int dks = 0; dks < 4; ++dks)
    qf[dks] = *(const bf16x8*)(qbase + dks * 16 + hi * 8);

  u32x4 onesw;
  onesw[0] = 0x3F803F80u; onesw[1] = 0x3F803F80u;
  onesw[2] = 0x3F803F80u; onesw[3] = 0x3F803F80u;
  const bf16x8 ones = __builtin_bit_cast(bf16x8, onesw);

  f32x16 acco0 = {}, acco1 = {};
  f32x16 accl = {};

  const char* kTile0 = (const char*)Kb + (size_t)bh * Mlen * 64 * 2;
  const char* vBase  = (const char*)Vt + (size_t)bh * 64 * Mlen * 2;

  auto stageKV = [&](int buf, int tile) {
    const int kv0 = tile * KVB;
#pragma unroll
    for (int i = 0; i < 2; ++i) {
      int idx = i * 256 + t;
      int L = idx * 16;
      int row = L >> 7;
      int inner = (L & 127) ^ ((row & 7) << 4);
      llds16(kTile0 + (size_t)(kv0 + row) * 128 + inner,
             (char*)(&Klds[buf][0]) + (i * 4 + w) * 1024);
    }
#pragma unroll
    for (int i = 0; i < 2; ++i) {
      int idx = i * 256 + t;
      int L = idx * 16;
      int d = L >> 7;
      int inner = (L & 127) ^ ((d & 7) << 4);
      llds16(vBase + (size_t)d * (Mlen * 2) + kv0 * 2 + inner,
             (char*)(&Vlds[buf][0]) + (i * 4 + w) * 1024);
    }
  };

  auto STEP_HEAD = [&](int tile) {
    if (tile + 1 < NTT) {
      stageKV((tile + 1) & 3, tile + 1);
      asm volatile("s_waitcnt vmcnt(4)" ::: "memory");
    } else {
      asm volatile("s_waitcnt vmcnt(0)" ::: "memory");
    }
    __builtin_amdgcn_s_barrier();
    __builtin_amdgcn_sched_barrier(0);
  };
  auto QK = [&](int tile, f32x16& s0, f32x16& s1) {
    const char* kb_ = (const char*)(&Klds[tile & 3][0]);
    __builtin_amdgcn_s_setprio(1);
#pragma unroll
    for (int dks = 0; dks < 4; ++dks) {
      const int a0 = (0 * 32 + l31) * 128 + ((dks * 32 + hi * 16) ^ key);
      const int a1 = (1 * 32 + l31) * 128 + ((dks * 32 + hi * 16) ^ key);
      bf16x8 kf0 = *(const bf16x8*)(kb_ + a0);
      bf16x8 kf1 = *(const bf16x8*)(kb_ + a1);
      s0 = __builtin_amdgcn_mfma_f32_32x32x16_bf16(kf0, qf[dks], s0, 0, 0, 0);
      s1 = __builtin_amdgcn_mfma_f32_32x32x16_bf16(kf1, qf[dks], s1, 0, 0, 0);
    }
    __builtin_amdgcn_s_setprio(0);
  };
  auto EXP = [&](const f32x16& s0, const f32x16& s1, u32 (&w0)[8], u32 (&w1)[8]) {
#pragma unroll
    for (int e2 = 0; e2 < 8; ++e2) {
      const float p00 = __builtin_amdgcn_exp2f(s0[2 * e2]);
      const float p01 = __builtin_amdgcn_exp2f(s0[2 * e2 + 1]);
      const float p10 = __builtin_amdgcn_exp2f(s1[2 * e2]);
      const float p11 = __builtin_amdgcn_exp2f(s1[2 * e2 + 1]);
      bf16x2 k0; k0[0] = (bf16)p00; k0[1] = (bf16)p01;
      bf16x2 k1; k1[0] = (bf16)p10; k1[1] = (bf16)p11;
      w0[e2] = __builtin_bit_cast(u32, k0);
      w1[e2] = __builtin_bit_cast(u32, k1);
    }
  };
  auto PV = [&](int tprev, const u32 (&w0)[8], const u32 (&w1)[8]) {
    const char* vb_ = (const char*)(&Vlds[tprev & 3][0]);
    __builtin_amdgcn_s_setprio(1);
#pragma unroll
    for (int ks = 0; ks < 2; ++ks) {
      auto sa0 = __builtin_amdgcn_permlane32_swap(w0[4 * ks + 0], w0[4 * ks + 2], false, false);
      auto sa1 = __builtin_amdgcn_permlane32_swap(w0[4 * ks + 1], w0[4 * ks + 3], false, false);
      auto sb0 = __builtin_amdgcn_permlane32_swap(w1[4 * ks + 0], w1[4 * ks + 2], false, false);
      auto sb1 = __builtin_amdgcn_permlane32_swap(w1[4 * ks + 1], w1[4 * ks + 3], false, false);
      u32x4 fa, fb;
      fa[0] = (u32)sa0[0]; fa[1] = (u32)sa1[0]; fa[2] = (u32)sa0[1]; fa[3] = (u32)sa1[1];
      fb[0] = (u32)sb0[0]; fb[1] = (u32)sb1[0]; fb[2] = (u32)sb0[1]; fb[3] = (u32)sb1[1];
      const bf16x8 pa = __builtin_bit_cast(bf16x8, fa);
      const bf16x8 pb = __builtin_bit_cast(bf16x8, fb);
      const int c0 = (ks * 32 + hi * 16);
      bf16x8 va0 = *(const bf16x8*)(vb_ + (0 * 32 + l31) * 128 + ((0 * 64 + c0) ^ key));
      bf16x8 va1 = *(const bf16x8*)(vb_ + (1 * 32 + l31) * 128 + ((0 * 64 + c0) ^ key));
      bf16x8 vb0 = *(const bf16x8*)(vb_ + (0 * 32 + l31) * 128 + ((1 * 64 + c0) ^ key));
      bf16x8 vb1 = *(const bf16x8*)(vb_ + (1 * 32 + l31) * 128 + ((1 * 64 + c0) ^ key));
      acco0 = __builtin_amdgcn_mfma_f32_32x32x16_bf16(pa, va0, acco0, 0, 0, 0);
      acco1 = __builtin_amdgcn_mfma_f32_32x32x16_bf16(pa, va1, acco1, 0, 0, 0);
      accl  = __builtin_amdgcn_mfma_f32_32x32x16_bf16(pa, ones, accl, 0, 0, 0);
      acco0 = __builtin_amdgcn_mfma_f32_32x32x16_bf16(pb, vb0, acco0, 0, 0, 0);
      acco1 = __builtin_amdgcn_mfma_f32_32x32x16_bf16(pb, vb1, acco1, 0, 0, 0);
      accl  = __builtin_amdgcn_mfma_f32_32x32x16_bf16(pb, ones, accl, 0, 0, 0);
    }
    __builtin_amdgcn_s_setprio(0);
  };

  u32 wE0[8], wE1[8], wO0[8], wO1[8];
  f32x16 s0, s1;

  stageKV(0, 0);
  // tile 0 (no PV yet)
  STEP_HEAD(0);
  s0 = f32x16{}; s1 = f32x16{};
  QK(0, s0, s1);
  EXP(s0, s1, wE0, wE1);
  // tiles 1..30 in pairs (odd uses wE as prev, writes wO; even vice versa)
  for (int tp = 0; tp < 15; ++tp) {
    const int to = 2 * tp + 1;
    STEP_HEAD(to);
    s0 = f32x16{}; s1 = f32x16{};
    QK(to, s0, s1);
    PV(to - 1, wE0, wE1);
    EXP(s0, s1, wO0, wO1);
    const int te = to + 1;
    STEP_HEAD(te);
    s0 = f32x16{}; s1 = f32x16{};
    QK(te, s0, s1);
    PV(te - 1, wO0, wO1);
    EXP(s0, s1, wE0, wE1);
  }
  // tile 31
  STEP_HEAD(31);
  s0 = f32x16{}; s1 = f32x16{};
  QK(31, s0, s1);
  PV(30, wE0, wE1);
  EXP(s0, s1, wO0, wO1);
  PV(31, wO0, wO1);

  // epilogue: per-element divide; accl[e] is the denominator for acco*[e]'s q
  const int b = bh >> 4, h = bh & 15;
#pragma unroll
  for (int e = 0; e < 16; ++e) {
    const int ql = (e & 3) + 8 * (e >> 2) + 4 * hi;
    const float iv = 1.0f / accl[e];
    const size_t row = (size_t)(b * 2048 + qr + ql) * 1024 + h * 64;
    Out[row + l31]      = (bf16)(acco0[e] * iv);
    Out[row + 32 + l31] = (bf16)(acco1[e] * iv);
  }
}

// ---------------- launch ----------------
extern "C" void kernel_launch(void* const* d_in, const int* in_sizes, int n_in,
                              void* d_out, int out_size, void* d_ws, size_t ws_size,
                              hipStream_t stream) {
  const float* q  = (const float*)d_in[0];
  const float* k  = (const float*)d_in[1];
  const float* v  = (const float*)d_in[2];
  const float* Wq = (const float*)d_in[3];
  const float* Wk = (const float*)d_in[4];
  const float* Wv = (const float*)d_in[5];
  const float* Wo = (const float*)d_in[6];

  char* ws = (char*)d_ws;
  const dim3 cb(256);

  if (ws_size >= ((size_t)56 << 20)) {
    // Wb@0(8M); Xq/Xk/Xv@8/16/24; qb/kb/vb@32/40/48; Xa@8 (reuse Xq)
    bf16* Wb = (bf16*)ws;
    bf16* Xq = (bf16*)(ws + (8u  << 20));
    bf16* Xk = (bf16*)(ws + (16u << 20));
    bf16* Xv = (bf16*)(ws + (24u << 20));
    bf16* qb = (bf16*)(ws + (32u << 20));
    bf16* kb = (bf16*)(ws + (40u << 20));
    bf16* vb = (bf16*)(ws + (48u << 20));
    bf16* Xa = (bf16*)(ws + (8u  << 20));

    cvt_all<<<8192, cb, 0, stream>>>(Wq, Wk, Wv, Wo, q, k, v, Wb, Xq);
    gemm_qkv<<<dim3(32, 8, 3), cb, 0, stream>>>(Xq, Xk, Xv, Wb, qb, kb, vb, 0);
    attn_fwd<<<512, cb, 0, stream>>>(qb, kb, vb, Xa);
    gemm_out<<<dim3(32, 16), cb, 0, stream>>>(Xa, Wb + 3 * (1u << 20), (float*)d_out);
  } else {
    // serial fallback (40MB): Wb@0, X@8 (shared), qb@16, kb@24, vb@32, Xa@8
    bf16* Wb = (bf16*)ws;
    bf16* X  = (bf16*)(ws + (8u  << 20));
    bf16* qb = (bf16*)(ws + (16u << 20));
    bf16* kb = (bf16*)(ws + (24u << 20));
    bf16* vb = (bf16*)(ws + (32u << 20));
    bf16* Xa = (bf16*)(ws + (8u  << 20));

    cvt_all<<<2048, cb, 0, stream>>>(Wq, Wk, Wv, Wo, q, k, v, Wb, Wb); // weights only
    cvt_bf16<<<2048, cb, 0, stream>>>(q, X, 524288);
    gemm_qkv<<<dim3(32, 8, 1), cb, 0, stream>>>(X, X, X, Wb, qb, kb, vb, 0);
    cvt_bf16<<<2048, cb, 0, stream>>>(k, X, 524288);
    gemm_qkv<<<dim3(32, 8, 1), cb, 0, stream>>>(X, X, X, Wb, qb, kb, vb, 1);
    cvt_bf16<<<2048, cb, 0, stream>>>(v, X, 524288);
    gemm_qkv<<<dim3(32, 8, 1), cb, 0, stream>>>(X, X, X, Wb, qb, kb, vb, 2);
    attn_fwd<<<512, cb, 0, stream>>>(qb, kb, vb, Xa);
    gemm_out<<<dim3(32, 16), cb, 0, stream>>>(Xa, Wb + 3 * (1u << 20), (float*)d_out);
  }
}

// Round 17
// 120.553 us; speedup vs baseline: 1.0580x; 1.0033x over previous
//
#include <hip/hip_runtime.h>

// ---------------- types ----------------
typedef __bf16 bf16;
typedef __bf16 bf16x2 __attribute__((ext_vector_type(2)));
typedef __bf16 bf16x8 __attribute__((ext_vector_type(8)));
typedef float  f32x4  __attribute__((ext_vector_type(4)));
typedef float  f32x16 __attribute__((ext_vector_type(16)));
typedef unsigned int u32;
typedef unsigned int u32x4 __attribute__((ext_vector_type(4)));

typedef __attribute__((address_space(1))) unsigned int gu32;
typedef __attribute__((address_space(3))) unsigned int lu32;

// async global->LDS, 16B per lane; LDS dest = wave-uniform base + lane*16
__device__ __forceinline__ void llds16(const void* g, void* l) {
  __builtin_amdgcn_global_load_lds((gu32*)g, (lu32*)l, 16, 0, 0);
}

// ---------------- fp32 -> bf16 converts (vectorized, 8 elems/thread) -------
__device__ __forceinline__ void cvt8(const float* __restrict__ src,
                                     bf16* __restrict__ dst, int i) {
  const float4* s4 = (const float4*)src;
  float4 a = s4[i * 2 + 0];
  float4 c = s4[i * 2 + 1];
  bf16x8 o;
  o[0] = (bf16)a.x; o[1] = (bf16)a.y; o[2] = (bf16)a.z; o[3] = (bf16)a.w;
  o[4] = (bf16)c.x; o[5] = (bf16)c.y; o[6] = (bf16)c.z; o[7] = (bf16)c.w;
  ((bf16x8*)dst)[i] = o;
}

__global__ __launch_bounds__(256) void cvt_bf16(const float* __restrict__ src,
                                                bf16* __restrict__ dst, int n8) {
  int i = blockIdx.x * blockDim.x + threadIdx.x;
  if (i < n8) cvt8(src, dst, i);
}

// ONE launch for all 7 fp32->bf16 conversions
__global__ __launch_bounds__(256) void cvt_all(const float* __restrict__ w0,
                                               const float* __restrict__ w1,
                                               const float* __restrict__ w2,
                                               const float* __restrict__ w3,
                                               const float* __restrict__ x0,
                                               const float* __restrict__ x1,
                                               const float* __restrict__ x2,
                                               bf16* __restrict__ wdst,
                                               bf16* __restrict__ xdst) {
  const int b = blockIdx.x;
  if (b < 2048) {
    const int which = b >> 9;
    const float* src = (which == 0) ? w0 : (which == 1) ? w1 : (which == 2) ? w2 : w3;
    const int i = (b & 511) * 256 + threadIdx.x;
    cvt8(src, wdst + (size_t)which * (1u << 20), i);
  } else {
    const int b2 = b - 2048;
    const int which = b2 >> 11;
    const float* src = (which == 0) ? x0 : (which == 1) ? x1 : x2;
    const int i = (b2 & 2047) * 256 + threadIdx.x;
    cvt8(src, xdst + (size_t)which * (4u << 20), i);
  }
}

// ---------------- QKV projection GEMM (bf16 A via global_load_lds) ---------
// z -> (q,k,v). 128x128 tile, BK=32, 4 waves of 64x64. NEW: row-paired LDS
// layout [64 rowpairs][128B] (rowpair p = rows 2p,2p+1; chunk c = (row&1)*4
// + kchunk), XOR-swizzled c^(p&7) per rule #21 -> fragment ds_read_b128 is
// conflict-free (was 8-way on 64B rows). Same LDS size/occupancy.
// z<2: C -> bf16 [B,H,M,D]; z==2: [B,H,D,M]. z==0 pre-scaled by 0.125*log2e.
__global__ __launch_bounds__(256) void gemm_qkv(const bf16* __restrict__ A0,
                                                const bf16* __restrict__ A1,
                                                const bf16* __restrict__ A2,
                                                const bf16* __restrict__ Wb,
                                                bf16* __restrict__ qb,
                                                bf16* __restrict__ kb,
                                                bf16* __restrict__ vb,
                                                int zoff) {
  constexpr int K = 1024, BM = 128, BN = 128, BK = 32, NT = K / BK;
  __shared__ bf16 Alds[2][BM * BK];   // [64 rowpairs][128B], 8KB per buf
  __shared__ bf16 Blds[2][BN * BK];
  const int t = threadIdx.x, w = t >> 6, l = t & 63;
  const int lr = l & 15, lg = l >> 4;
  const int bm = blockIdx.x * BM, bn = blockIdx.y * BN;
  const int z = blockIdx.z + zoff;
  const bf16* A = (z == 0) ? A0 : (z == 1) ? A1 : A2;
  const bf16* W = Wb + (size_t)z * (1u << 20);
  const int wm = (w >> 1) * 64, wn = (w & 1) * 64;

  f32x4 acc[4][4] = {};

  // stage one tile: 512 chunks; slot q of rowpair p holds global chunk
  // c' = q^(p&7) = (row 2p+(c'>>2), 64B-chunk c'&3)
  auto stage = [&](int buf, int kt) {
    const int k0 = kt * BK;
#pragma unroll
    for (int i = 0; i < 2; ++i) {
      int idx = i * 256 + t;
      int p = idx >> 3, q = idx & 7;
      int c = q ^ (p & 7);
      llds16((const char*)A + ((size_t)(bm + 2 * p + (c >> 2)) * K + k0) * 2 + (c & 3) * 16,
             (char*)(&Alds[buf][0]) + (i * 4 + w) * 1024);
    }
#pragma unroll
    for (int i = 0; i < 2; ++i) {
      int idx = i * 256 + t;
      int p = idx >> 3, q = idx & 7;
      int c = q ^ (p & 7);
      llds16((const char*)W + ((size_t)(bn + 2 * p + (c >> 2)) * K + k0) * 2 + (c & 3) * 16,
             (char*)(&Blds[buf][0]) + (i * 4 + w) * 1024);
    }
  };

  stage(0, 0);
  for (int kt = 0; kt < NT; ++kt) {
    __syncthreads();
    if (kt + 1 < NT) stage((kt + 1) & 1, kt + 1);
    const int cur = kt & 1;
    bf16x8 af[4], bfr[4];
#pragma unroll
    for (int i = 0; i < 4; ++i) {
      const int row = wm + i * 16 + lr;
      const int p = row >> 1, h = row & 1;
      af[i] = *(const bf16x8*)((const char*)(&Alds[cur][0]) + p * 128 +
                               (((h * 4 + lg) ^ (p & 7)) * 16));
    }
#pragma unroll
    for (int j = 0; j < 4; ++j) {
      const int row = wn + j * 16 + lr;
      const int p = row >> 1, h = row & 1;
      bfr[j] = *(const bf16x8*)((const char*)(&Blds[cur][0]) + p * 128 +
                                (((h * 4 + lg) ^ (p & 7)) * 16));
    }
    __builtin_amdgcn_s_setprio(1);
#pragma unroll
    for (int i = 0; i < 4; ++i)
#pragma unroll
      for (int j = 0; j < 4; ++j)
        acc[i][j] = __builtin_amdgcn_mfma_f32_16x16x32_bf16(af[i], bfr[j], acc[i][j], 0, 0, 0);
    __builtin_amdgcn_s_setprio(0);
  }

  bf16* Cout = (z == 0) ? qb : (z == 1) ? kb : vb;
  const float osc = (z == 0) ? 0.1803368801f : 1.0f;   // 0.125 * log2(e)
#pragma unroll
  for (int i = 0; i < 4; ++i) {
#pragma unroll
    for (int j = 0; j < 4; ++j) {
#pragma unroll
      for (int r = 0; r < 4; ++r) {
        const int gm = bm + wm + i * 16 + lg * 4 + r;
        const int n  = bn + wn + j * 16 + lr;
        const int b = gm >> 11, m = gm & 2047;
        const int h = n >> 6, d = n & 63;
        const size_t off = (z < 2)
            ? ((size_t)((b * 16 + h) * 2048 + m) * 64 + d)
            : ((size_t)((b * 16 + h) * 64 + d) * 2048 + m);
        Cout[off] = (bf16)(acc[i][j][r] * osc);
      }
    }
  }
}

// ---------------- output GEMM: C = A(MxK).B(NxK)^T -> f32 [M,N] ------------
// 128x64 tile, BK=64 (16 MFMA per barrier, 16 K-iters). 128B LDS rows are
// XOR-swizzled per rule #21. Grid (32,16) = 512 blocks. (r16 proven)
__global__ __launch_bounds__(256) void gemm_out(const bf16* __restrict__ A,
                                                const bf16* __restrict__ Bw,
                                                float* __restrict__ Cout) {
  constexpr int N = 1024, K = 1024;
  constexpr int BM = 128, BN = 64, BK = 64, NT = K / BK;
  __shared__ bf16 Alds[2][BM * BK];   // 16KB per buf
  __shared__ bf16 Blds[2][BN * BK];   // 8KB per buf
  const int t = threadIdx.x;
  const int w = t >> 6, l = t & 63;
  const int lr = l & 15, lg = l >> 4;
  const int bm = blockIdx.x * BM, bn = blockIdx.y * BN;
  const int wm = (w >> 1) * 64, wn = (w & 1) * 32;
  const int key = (lr & 7) << 4;       // read-side swizzle key

  f32x4 acc[4][2] = {};

  auto stage = [&](int buf, int kt) {
    const int k0 = kt * BK;
#pragma unroll
    for (int i = 0; i < 4; ++i) {
      int idx = i * 256 + t;
      int row = idx >> 3, c = idx & 7;
      llds16((const char*)A + ((size_t)(bm + row) * K + k0) * 2 + ((c ^ (row & 7)) * 16),
             (char*)(&Alds[buf][0]) + (i * 4 + w) * 1024);
    }
#pragma unroll
    for (int i = 0; i < 2; ++i) {
      int idx = i * 256 + t;
      int row = idx >> 3, c = idx & 7;
      llds16((const char*)Bw + ((size_t)(bn + row) * K + k0) * 2 + ((c ^ (row & 7)) * 16),
             (char*)(&Blds[buf][0]) + (i * 4 + w) * 1024);
    }
  };

  stage(0, 0);
  for (int kt = 0; kt < NT; ++kt) {
    __syncthreads();
    if (kt + 1 < NT) stage((kt + 1) & 1, kt + 1);
    const int cur = kt & 1;
    bf16x8 af[4][2], bfr[2][2];
#pragma unroll
    for (int i = 0; i < 4; ++i) {
      const int row = wm + i * 16 + lr;
      const char* rb = (const char*)(&Alds[cur][0]) + row * 128;
#pragma unroll
      for (int kk = 0; kk < 2; ++kk)
        af[i][kk] = *(const bf16x8*)(rb + ((kk * 64 + lg * 16) ^ key));
    }
#pragma unroll
    for (int j = 0; j < 2; ++j) {
      const int row = wn + j * 16 + lr;
      const char* rb = (const char*)(&Blds[cur][0]) + row * 128;
#pragma unroll
      for (int kk = 0; kk < 2; ++kk)
        bfr[j][kk] = *(const bf16x8*)(rb + ((kk * 64 + lg * 16) ^ key));
    }
    __builtin_amdgcn_s_setprio(1);
#pragma unroll
    for (int kk = 0; kk < 2; ++kk)
#pragma unroll
      for (int i = 0; i < 4; ++i)
#pragma unroll
        for (int j = 0; j < 2; ++j)
          acc[i][j] = __builtin_amdgcn_mfma_f32_16x16x32_bf16(af[i][kk], bfr[j][kk], acc[i][j], 0, 0, 0);
    __builtin_amdgcn_s_setprio(0);
  }

#pragma unroll
  for (int i = 0; i < 4; ++i)
#pragma unroll
    for (int j = 0; j < 2; ++j)
#pragma unroll
      for (int r = 0; r < 4; ++r) {
        const int gm = bm + wm + i * 16 + lg * 4 + r;
        const int n  = bn + wn + j * 16 + lr;
        Cout[(size_t)gm * N + n] = acc[i][j][r];
      }
}

// ---------------- flash attention: rotated software pipeline (r14 exact) ---
__global__ __launch_bounds__(256) void attn_fwd(const bf16* __restrict__ Qb,
                                                const bf16* __restrict__ Kb,
                                                const bf16* __restrict__ Vt,
                                                bf16* __restrict__ Out) {
  constexpr int Mlen = 2048, KVB = 64, NTT = Mlen / KVB;
  __shared__ bf16 Klds[4][KVB * 64];   // [kv][d] 128B rows, swizzled (32KB)
  __shared__ bf16 Vlds[4][64 * KVB];   // [d][kv] 128B rows, swizzled (32KB)
  const int t = threadIdx.x, w = t >> 6, l = t & 63;
  const int l31 = l & 31, hi = l >> 5;
  const int orig = blockIdx.x;
  const int wg = (orig & 7) * 64 + (orig >> 3);   // XCD bijective swizzle
  const int bh = wg >> 4;
  const int qr = (wg & 15) * 128 + w * 32;
  const int key = (l31 & 7) << 4;

  const bf16* qbase = Qb + ((size_t)bh * Mlen + qr + l31) * 64;
  bf16x8 qf[4];
#pragma unroll
  for (int dks = 0; dks < 4; ++dks)
    qf[dks] = *(const bf16x8*)(qbase + dks * 16 + hi * 8);

  u32x4 onesw;
  onesw[0] = 0x3F803F80u; onesw[1] = 0x3F803F80u;
  onesw[2] = 0x3F803F80u; onesw[3] = 0x3F803F80u;
  const bf16x8 ones = __builtin_bit_cast(bf16x8, onesw);

  f32x16 acco0 = {}, acco1 = {};
  f32x16 accl = {};

  const char* kTile0 = (const char*)Kb + (size_t)bh * Mlen * 64 * 2;
  const char* vBase  = (const char*)Vt + (size_t)bh * 64 * Mlen * 2;

  auto stageKV = [&](int buf, int tile) {
    const int kv0 = tile * KVB;
#pragma unroll
    for (int i = 0; i < 2; ++i) {
      int idx = i * 256 + t;
      int L = idx * 16;
      int row = L >> 7;
      int inner = (L & 127) ^ ((row & 7) << 4);
      llds16(kTile0 + (size_t)(kv0 + row) * 128 + inner,
             (char*)(&Klds[buf][0]) + (i * 4 + w) * 1024);
    }
#pragma unroll
    for (int i = 0; i < 2; ++i) {
      int idx = i * 256 + t;
      int L = idx * 16;
      int d = L >> 7;
      int inner = (L & 127) ^ ((d & 7) << 4);
      llds16(vBase + (size_t)d * (Mlen * 2) + kv0 * 2 + inner,
             (char*)(&Vlds[buf][0]) + (i * 4 + w) * 1024);
    }
  };

  auto STEP_HEAD = [&](int tile) {
    if (tile + 1 < NTT) {
      stageKV((tile + 1) & 3, tile + 1);
      asm volatile("s_waitcnt vmcnt(4)" ::: "memory");
    } else {
      asm volatile("s_waitcnt vmcnt(0)" ::: "memory");
    }
    __builtin_amdgcn_s_barrier();
    __builtin_amdgcn_sched_barrier(0);
  };
  auto QK = [&](int tile, f32x16& s0, f32x16& s1) {
    const char* kb_ = (const char*)(&Klds[tile & 3][0]);
    __builtin_amdgcn_s_setprio(1);
#pragma unroll
    for (int dks = 0; dks < 4; ++dks) {
      const int a0 = (0 * 32 + l31) * 128 + ((dks * 32 + hi * 16) ^ key);
      const int a1 = (1 * 32 + l31) * 128 + ((dks * 32 + hi * 16) ^ key);
      bf16x8 kf0 = *(const bf16x8*)(kb_ + a0);
      bf16x8 kf1 = *(const bf16x8*)(kb_ + a1);
      s0 = __builtin_amdgcn_mfma_f32_32x32x16_bf16(kf0, qf[dks], s0, 0, 0, 0);
      s1 = __builtin_amdgcn_mfma_f32_32x32x16_bf16(kf1, qf[dks], s1, 0, 0, 0);
    }
    __builtin_amdgcn_s_setprio(0);
  };
  auto EXP = [&](const f32x16& s0, const f32x16& s1, u32 (&w0)[8], u32 (&w1)[8]) {
#pragma unroll
    for (int e2 = 0; e2 < 8; ++e2) {
      const float p00 = __builtin_amdgcn_exp2f(s0[2 * e2]);
      const float p01 = __builtin_amdgcn_exp2f(s0[2 * e2 + 1]);
      const float p10 = __builtin_amdgcn_exp2f(s1[2 * e2]);
      const float p11 = __builtin_amdgcn_exp2f(s1[2 * e2 + 1]);
      bf16x2 k0; k0[0] = (bf16)p00; k0[1] = (bf16)p01;
      bf16x2 k1; k1[0] = (bf16)p10; k1[1] = (bf16)p11;
      w0[e2] = __builtin_bit_cast(u32, k0);
      w1[e2] = __builtin_bit_cast(u32, k1);
    }
  };
  auto PV = [&](int tprev, const u32 (&w0)[8], const u32 (&w1)[8]) {
    const char* vb_ = (const char*)(&Vlds[tprev & 3][0]);
    __builtin_amdgcn_s_setprio(1);
#pragma unroll
    for (int ks = 0; ks < 2; ++ks) {
      auto sa0 = __builtin_amdgcn_permlane32_swap(w0[4 * ks + 0], w0[4 * ks + 2], false, false);
      auto sa1 = __builtin_amdgcn_permlane32_swap(w0[4 * ks + 1], w0[4 * ks + 3], false, false);
      auto sb0 = __builtin_amdgcn_permlane32_swap(w1[4 * ks + 0], w1[4 * ks + 2], false, false);
      auto sb1 = __builtin_amdgcn_permlane32_swap(w1[4 * ks + 1], w1[4 * ks + 3], false, false);
      u32x4 fa, fb;
      fa[0] = (u32)sa0[0]; fa[1] = (u32)sa1[0]; fa[2] = (u32)sa0[1]; fa[3] = (u32)sa1[1];
      fb[0] = (u32)sb0[0]; fb[1] = (u32)sb1[0]; fb[2] = (u32)sb0[1]; fb[3] = (u32)sb1[1];
      const bf16x8 pa = __builtin_bit_cast(bf16x8, fa);
      const bf16x8 pb = __builtin_bit_cast(bf16x8, fb);
      const int c0 = (ks * 32 + hi * 16);
      bf16x8 va0 = *(const bf16x8*)(vb_ + (0 * 32 + l31) * 128 + ((0 * 64 + c0) ^ key));
      bf16x8 va1 = *(const bf16x8*)(vb_ + (1 * 32 + l31) * 128 + ((0 * 64 + c0) ^ key));
      bf16x8 vb0 = *(const bf16x8*)(vb_ + (0 * 32 + l31) * 128 + ((1 * 64 + c0) ^ key));
      bf16x8 vb1 = *(const bf16x8*)(vb_ + (1 * 32 + l31) * 128 + ((1 * 64 + c0) ^ key));
      acco0 = __builtin_amdgcn_mfma_f32_32x32x16_bf16(pa, va0, acco0, 0, 0, 0);
      acco1 = __builtin_amdgcn_mfma_f32_32x32x16_bf16(pa, va1, acco1, 0, 0, 0);
      accl  = __builtin_amdgcn_mfma_f32_32x32x16_bf16(pa, ones, accl, 0, 0, 0);
      acco0 = __builtin_amdgcn_mfma_f32_32x32x16_bf16(pb, vb0, acco0, 0, 0, 0);
      acco1 = __builtin_amdgcn_mfma_f32_32x32x16_bf16(pb, vb1, acco1, 0, 0, 0);
      accl  = __builtin_amdgcn_mfma_f32_32x32x16_bf16(pb, ones, accl, 0, 0, 0);
    }
    __builtin_amdgcn_s_setprio(0);
  };

  u32 wE0[8], wE1[8], wO0[8], wO1[8];
  f32x16 s0, s1;

  stageKV(0, 0);
  STEP_HEAD(0);
  s0 = f32x16{}; s1 = f32x16{};
  QK(0, s0, s1);
  EXP(s0, s1, wE0, wE1);
  for (int tp = 0; tp < 15; ++tp) {
    const int to = 2 * tp + 1;
    STEP_HEAD(to);
    s0 = f32x16{}; s1 = f32x16{};
    QK(to, s0, s1);
    PV(to - 1, wE0, wE1);
    EXP(s0, s1, wO0, wO1);
    const int te = to + 1;
    STEP_HEAD(te);
    s0 = f32x16{}; s1 = f32x16{};
    QK(te, s0, s1);
    PV(te - 1, wO0, wO1);
    EXP(s0, s1, wE0, wE1);
  }
  STEP_HEAD(31);
  s0 = f32x16{}; s1 = f32x16{};
  QK(31, s0, s1);
  PV(30, wE0, wE1);
  EXP(s0, s1, wO0, wO1);
  PV(31, wO0, wO1);

  const int b = bh >> 4, h = bh & 15;
#pragma unroll
  for (int e = 0; e < 16; ++e) {
    const int ql = (e & 3) + 8 * (e >> 2) + 4 * hi;
    const float iv = 1.0f / accl[e];
    const size_t row = (size_t)(b * 2048 + qr + ql) * 1024 + h * 64;
    Out[row + l31]      = (bf16)(acco0[e] * iv);
    Out[row + 32 + l31] = (bf16)(acco1[e] * iv);
  }
}

// ---------------- launch ----------------
extern "C" void kernel_launch(void* const* d_in, const int* in_sizes, int n_in,
                              void* d_out, int out_size, void* d_ws, size_t ws_size,
                              hipStream_t stream) {
  const float* q  = (const float*)d_in[0];
  const float* k  = (const float*)d_in[1];
  const float* v  = (const float*)d_in[2];
  const float* Wq = (const float*)d_in[3];
  const float* Wk = (const float*)d_in[4];
  const float* Wv = (const float*)d_in[5];
  const float* Wo = (const float*)d_in[6];

  char* ws = (char*)d_ws;
  const dim3 cb(256);

  if (ws_size >= ((size_t)56 << 20)) {
    // Wb@0(8M); Xq/Xk/Xv@8/16/24; qb/kb/vb@32/40/48; Xa@8 (reuse Xq)
    bf16* Wb = (bf16*)ws;
    bf16* Xq = (bf16*)(ws + (8u  << 20));
    bf16* Xk = (bf16*)(ws + (16u << 20));
    bf16* Xv = (bf16*)(ws + (24u << 20));
    bf16* qb = (bf16*)(ws + (32u << 20));
    bf16* kb = (bf16*)(ws + (40u << 20));
    bf16* vb = (bf16*)(ws + (48u << 20));
    bf16* Xa = (bf16*)(ws + (8u  << 20));

    cvt_all<<<8192, cb, 0, stream>>>(Wq, Wk, Wv, Wo, q, k, v, Wb, Xq);
    gemm_qkv<<<dim3(32, 8, 3), cb, 0, stream>>>(Xq, Xk, Xv, Wb, qb, kb, vb, 0);
    attn_fwd<<<512, cb, 0, stream>>>(qb, kb, vb, Xa);
    gemm_out<<<dim3(32, 16), cb, 0, stream>>>(Xa, Wb + 3 * (1u << 20), (float*)d_out);
  } else {
    // serial fallback (40MB): Wb@0, X@8 (shared), qb@16, kb@24, vb@32, Xa@8
    bf16* Wb = (bf16*)ws;
    bf16* X  = (bf16*)(ws + (8u  << 20));
    bf16* qb = (bf16*)(ws + (16u << 20));
    bf16* kb = (bf16*)(ws + (24u << 20));
    bf16* vb = (bf16*)(ws + (32u << 20));
    bf16* Xa = (bf16*)(ws + (8u  << 20));

    cvt_all<<<2048, cb, 0, stream>>>(Wq, Wk, Wv, Wo, q, k, v, Wb, Wb); // weights only
    cvt_bf16<<<2048, cb, 0, stream>>>(q, X, 524288);
    gemm_qkv<<<dim3(32, 8, 1), cb, 0, stream>>>(X, X, X, Wb, qb, kb, vb, 0);
    cvt_bf16<<<2048, cb, 0, stream>>>(k, X, 524288);
    gemm_qkv<<<dim3(32, 8, 1), cb, 0, stream>>>(X, X, X, Wb, qb, kb, vb, 1);
    cvt_bf16<<<2048, cb, 0, stream>>>(v, X, 524288);
    gemm_qkv<<<dim3(32, 8, 1), cb, 0, stream>>>(X, X, X, Wb, qb, kb, vb, 2);
    attn_fwd<<<512, cb, 0, stream>>>(qb, kb, vb, Xa);
    gemm_out<<<dim3(32, 16), cb, 0, stream>>>(Xa, Wb + 3 * (1u << 20), (float*)d_out);
  }
}

// Round 18
// 118.447 us; speedup vs baseline: 1.0769x; 1.0178x over previous
//
#include <hip/hip_runtime.h>

// ---------------- types ----------------
typedef __bf16 bf16;
typedef __bf16 bf16x2 __attribute__((ext_vector_type(2)));
typedef __bf16 bf16x8 __attribute__((ext_vector_type(8)));
typedef float  f32x4  __attribute__((ext_vector_type(4)));
typedef float  f32x16 __attribute__((ext_vector_type(16)));
typedef unsigned int u32;
typedef unsigned int u32x4 __attribute__((ext_vector_type(4)));

typedef __attribute__((address_space(1))) unsigned int gu32;
typedef __attribute__((address_space(3))) unsigned int lu32;

// async global->LDS, 16B per lane; LDS dest = wave-uniform base + lane*16
__device__ __forceinline__ void llds16(const void* g, void* l) {
  __builtin_amdgcn_global_load_lds((gu32*)g, (lu32*)l, 16, 0, 0);
}

// ---------------- fp32 -> bf16 converts (vectorized, 8 elems/thread) -------
__device__ __forceinline__ void cvt8(const float* __restrict__ src,
                                     bf16* __restrict__ dst, int i) {
  const float4* s4 = (const float4*)src;
  float4 a = s4[i * 2 + 0];
  float4 c = s4[i * 2 + 1];
  bf16x8 o;
  o[0] = (bf16)a.x; o[1] = (bf16)a.y; o[2] = (bf16)a.z; o[3] = (bf16)a.w;
  o[4] = (bf16)c.x; o[5] = (bf16)c.y; o[6] = (bf16)c.z; o[7] = (bf16)c.w;
  ((bf16x8*)dst)[i] = o;
}

__global__ __launch_bounds__(256) void cvt_bf16(const float* __restrict__ src,
                                                bf16* __restrict__ dst, int n8) {
  int i = blockIdx.x * blockDim.x + threadIdx.x;
  if (i < n8) cvt8(src, dst, i);
}

// ONE launch for all 7 fp32->bf16 conversions
__global__ __launch_bounds__(256) void cvt_all(const float* __restrict__ w0,
                                               const float* __restrict__ w1,
                                               const float* __restrict__ w2,
                                               const float* __restrict__ w3,
                                               const float* __restrict__ x0,
                                               const float* __restrict__ x1,
                                               const float* __restrict__ x2,
                                               bf16* __restrict__ wdst,
                                               bf16* __restrict__ xdst) {
  const int b = blockIdx.x;
  if (b < 2048) {
    const int which = b >> 9;
    const float* src = (which == 0) ? w0 : (which == 1) ? w1 : (which == 2) ? w2 : w3;
    const int i = (b & 511) * 256 + threadIdx.x;
    cvt8(src, wdst + (size_t)which * (1u << 20), i);
  } else {
    const int b2 = b - 2048;
    const int which = b2 >> 11;
    const float* src = (which == 0) ? x0 : (which == 1) ? x1 : x2;
    const int i = (b2 & 2047) * 256 + threadIdx.x;
    cvt8(src, xdst + (size_t)which * (4u << 20), i);
  }
}

// ---------------- QKV projection GEMM (bf16 A via global_load_lds) ---------
// z -> (q,k,v). 128x128 tile, BK=32, 4 waves of 64x64, row-paired swizzled
// LDS (r17). NEW: 3-buf counted-vmcnt pipeline (attn-r7 pattern): stage(t+1)
// issued before {vmcnt(4); barrier}, so stage(t+1)'s 4 loads stay in flight
// across the barrier -- no full drain per K-step. 48KB LDS -> 3 blocks/CU.
// z<2: C -> bf16 [B,H,M,D]; z==2: [B,H,D,M]. z==0 pre-scaled by 0.125*log2e.
__global__ __launch_bounds__(256) void gemm_qkv(const bf16* __restrict__ A0,
                                                const bf16* __restrict__ A1,
                                                const bf16* __restrict__ A2,
                                                const bf16* __restrict__ Wb,
                                                bf16* __restrict__ qb,
                                                bf16* __restrict__ kb,
                                                bf16* __restrict__ vb,
                                                int zoff) {
  constexpr int K = 1024, BM = 128, BN = 128, BK = 32, NT = K / BK;
  __shared__ bf16 Alds[3][BM * BK];   // [64 rowpairs][128B], 8KB per buf
  __shared__ bf16 Blds[3][BN * BK];
  const int t = threadIdx.x, w = t >> 6, l = t & 63;
  const int lr = l & 15, lg = l >> 4;
  const int bm = blockIdx.x * BM, bn = blockIdx.y * BN;
  const int z = blockIdx.z + zoff;
  const bf16* A = (z == 0) ? A0 : (z == 1) ? A1 : A2;
  const bf16* W = Wb + (size_t)z * (1u << 20);
  const int wm = (w >> 1) * 64, wn = (w & 1) * 64;

  f32x4 acc[4][4] = {};

  // stage one tile: slot q of rowpair p holds global chunk c' = q^(p&7)
  auto stage = [&](int buf, int kt) {
    const int k0 = kt * BK;
#pragma unroll
    for (int i = 0; i < 2; ++i) {
      int idx = i * 256 + t;
      int p = idx >> 3, q = idx & 7;
      int c = q ^ (p & 7);
      llds16((const char*)A + ((size_t)(bm + 2 * p + (c >> 2)) * K + k0) * 2 + (c & 3) * 16,
             (char*)(&Alds[buf][0]) + (i * 4 + w) * 1024);
    }
#pragma unroll
    for (int i = 0; i < 2; ++i) {
      int idx = i * 256 + t;
      int p = idx >> 3, q = idx & 7;
      int c = q ^ (p & 7);
      llds16((const char*)W + ((size_t)(bn + 2 * p + (c >> 2)) * K + k0) * 2 + (c & 3) * 16,
             (char*)(&Blds[buf][0]) + (i * 4 + w) * 1024);
    }
  };

  stage(0, 0);
  int bufc = 0;
  for (int kt = 0; kt < NT; ++kt) {
    const int bufn = (bufc == 2) ? 0 : bufc + 1;
    if (kt + 1 < NT) {
      stage(bufn, kt + 1);
      asm volatile("s_waitcnt vmcnt(4)" ::: "memory");   // stage(kt) retired
    } else {
      asm volatile("s_waitcnt vmcnt(0)" ::: "memory");
    }
    __builtin_amdgcn_s_barrier();
    __builtin_amdgcn_sched_barrier(0);
    bf16x8 af[4], bfr[4];
#pragma unroll
    for (int i = 0; i < 4; ++i) {
      const int row = wm + i * 16 + lr;
      const int p = row >> 1, h = row & 1;
      af[i] = *(const bf16x8*)((const char*)(&Alds[bufc][0]) + p * 128 +
                               (((h * 4 + lg) ^ (p & 7)) * 16));
    }
#pragma unroll
    for (int j = 0; j < 4; ++j) {
      const int row = wn + j * 16 + lr;
      const int p = row >> 1, h = row & 1;
      bfr[j] = *(const bf16x8*)((const char*)(&Blds[bufc][0]) + p * 128 +
                                (((h * 4 + lg) ^ (p & 7)) * 16));
    }
    __builtin_amdgcn_s_setprio(1);
#pragma unroll
    for (int i = 0; i < 4; ++i)
#pragma unroll
      for (int j = 0; j < 4; ++j)
        acc[i][j] = __builtin_amdgcn_mfma_f32_16x16x32_bf16(af[i], bfr[j], acc[i][j], 0, 0, 0);
    __builtin_amdgcn_s_setprio(0);
    bufc = bufn;
  }

  bf16* Cout = (z == 0) ? qb : (z == 1) ? kb : vb;
  const float osc = (z == 0) ? 0.1803368801f : 1.0f;   // 0.125 * log2(e)
#pragma unroll
  for (int i = 0; i < 4; ++i) {
#pragma unroll
    for (int j = 0; j < 4; ++j) {
#pragma unroll
      for (int r = 0; r < 4; ++r) {
        const int gm = bm + wm + i * 16 + lg * 4 + r;
        const int n  = bn + wn + j * 16 + lr;
        const int b = gm >> 11, m = gm & 2047;
        const int h = n >> 6, d = n & 63;
        const size_t off = (z < 2)
            ? ((size_t)((b * 16 + h) * 2048 + m) * 64 + d)
            : ((size_t)((b * 16 + h) * 64 + d) * 2048 + m);
        Cout[off] = (bf16)(acc[i][j][r] * osc);
      }
    }
  }
}

// ---------------- output GEMM: C = A(MxK).B(NxK)^T -> f32 [M,N] ------------
// 128x64 tile, BK=64, swizzled 128B rows (r16) + 3-buf counted vmcnt(6).
// 72KB LDS -> 2 blocks/CU (= grid cap). Grid (32,16) = 512 blocks.
__global__ __launch_bounds__(256) void gemm_out(const bf16* __restrict__ A,
                                                const bf16* __restrict__ Bw,
                                                float* __restrict__ Cout) {
  constexpr int N = 1024, K = 1024;
  constexpr int BM = 128, BN = 64, BK = 64, NT = K / BK;
  __shared__ bf16 Alds[3][BM * BK];   // 16KB per buf
  __shared__ bf16 Blds[3][BN * BK];   // 8KB per buf
  const int t = threadIdx.x;
  const int w = t >> 6, l = t & 63;
  const int lr = l & 15, lg = l >> 4;
  const int bm = blockIdx.x * BM, bn = blockIdx.y * BN;
  const int wm = (w >> 1) * 64, wn = (w & 1) * 32;
  const int key = (lr & 7) << 4;       // read-side swizzle key

  f32x4 acc[4][2] = {};

  auto stage = [&](int buf, int kt) {
    const int k0 = kt * BK;
#pragma unroll
    for (int i = 0; i < 4; ++i) {
      int idx = i * 256 + t;
      int row = idx >> 3, c = idx & 7;
      llds16((const char*)A + ((size_t)(bm + row) * K + k0) * 2 + ((c ^ (row & 7)) * 16),
             (char*)(&Alds[buf][0]) + (i * 4 + w) * 1024);
    }
#pragma unroll
    for (int i = 0; i < 2; ++i) {
      int idx = i * 256 + t;
      int row = idx >> 3, c = idx & 7;
      llds16((const char*)Bw + ((size_t)(bn + row) * K + k0) * 2 + ((c ^ (row & 7)) * 16),
             (char*)(&Blds[buf][0]) + (i * 4 + w) * 1024);
    }
  };

  stage(0, 0);
  int bufc = 0;
  for (int kt = 0; kt < NT; ++kt) {
    const int bufn = (bufc == 2) ? 0 : bufc + 1;
    if (kt + 1 < NT) {
      stage(bufn, kt + 1);
      asm volatile("s_waitcnt vmcnt(6)" ::: "memory");   // stage(kt) retired
    } else {
      asm volatile("s_waitcnt vmcnt(0)" ::: "memory");
    }
    __builtin_amdgcn_s_barrier();
    __builtin_amdgcn_sched_barrier(0);
    bf16x8 af[4][2], bfr[2][2];
#pragma unroll
    for (int i = 0; i < 4; ++i) {
      const int row = wm + i * 16 + lr;
      const char* rb = (const char*)(&Alds[bufc][0]) + row * 128;
#pragma unroll
      for (int kk = 0; kk < 2; ++kk)
        af[i][kk] = *(const bf16x8*)(rb + ((kk * 64 + lg * 16) ^ key));
    }
#pragma unroll
    for (int j = 0; j < 2; ++j) {
      const int row = wn + j * 16 + lr;
      const char* rb = (const char*)(&Blds[bufc][0]) + row * 128;
#pragma unroll
      for (int kk = 0; kk < 2; ++kk)
        bfr[j][kk] = *(const bf16x8*)(rb + ((kk * 64 + lg * 16) ^ key));
    }
    __builtin_amdgcn_s_setprio(1);
#pragma unroll
    for (int kk = 0; kk < 2; ++kk)
#pragma unroll
      for (int i = 0; i < 4; ++i)
#pragma unroll
        for (int j = 0; j < 2; ++j)
          acc[i][j] = __builtin_amdgcn_mfma_f32_16x16x32_bf16(af[i][kk], bfr[j][kk], acc[i][j], 0, 0, 0);
    __builtin_amdgcn_s_setprio(0);
    bufc = bufn;
  }

#pragma unroll
  for (int i = 0; i < 4; ++i)
#pragma unroll
    for (int j = 0; j < 2; ++j)
#pragma unroll
      for (int r = 0; r < 4; ++r) {
        const int gm = bm + wm + i * 16 + lg * 4 + r;
        const int n  = bn + wn + j * 16 + lr;
        Cout[(size_t)gm * N + n] = acc[i][j][r];
      }
}

// ---------------- flash attention: rotated software pipeline (r14 exact) ---
__global__ __launch_bounds__(256) void attn_fwd(const bf16* __restrict__ Qb,
                                                const bf16* __restrict__ Kb,
                                                const bf16* __restrict__ Vt,
                                                bf16* __restrict__ Out) {
  constexpr int Mlen = 2048, KVB = 64, NTT = Mlen / KVB;
  __shared__ bf16 Klds[4][KVB * 64];   // [kv][d] 128B rows, swizzled (32KB)
  __shared__ bf16 Vlds[4][64 * KVB];   // [d][kv] 128B rows, swizzled (32KB)
  const int t = threadIdx.x, w = t >> 6, l = t & 63;
  const int l31 = l & 31, hi = l >> 5;
  const int orig = blockIdx.x;
  const int wg = (orig & 7) * 64 + (orig >> 3);   // XCD bijective swizzle
  const int bh = wg >> 4;
  const int qr = (wg & 15) * 128 + w * 32;
  const int key = (l31 & 7) << 4;

  const bf16* qbase = Qb + ((size_t)bh * Mlen + qr + l31) * 64;
  bf16x8 qf[4];
#pragma unroll
  for (int dks = 0; dks < 4; ++dks)
    qf[dks] = *(const bf16x8*)(qbase + dks * 16 + hi * 8);

  u32x4 onesw;
  onesw[0] = 0x3F803F80u; onesw[1] = 0x3F803F80u;
  onesw[2] = 0x3F803F80u; onesw[3] = 0x3F803F80u;
  const bf16x8 ones = __builtin_bit_cast(bf16x8, onesw);

  f32x16 acco0 = {}, acco1 = {};
  f32x16 accl = {};

  const char* kTile0 = (const char*)Kb + (size_t)bh * Mlen * 64 * 2;
  const char* vBase  = (const char*)Vt + (size_t)bh * 64 * Mlen * 2;

  auto stageKV = [&](int buf, int tile) {
    const int kv0 = tile * KVB;
#pragma unroll
    for (int i = 0; i < 2; ++i) {
      int idx = i * 256 + t;
      int L = idx * 16;
      int row = L >> 7;
      int inner = (L & 127) ^ ((row & 7) << 4);
      llds16(kTile0 + (size_t)(kv0 + row) * 128 + inner,
             (char*)(&Klds[buf][0]) + (i * 4 + w) * 1024);
    }
#pragma unroll
    for (int i = 0; i < 2; ++i) {
      int idx = i * 256 + t;
      int L = idx * 16;
      int d = L >> 7;
      int inner = (L & 127) ^ ((d & 7) << 4);
      llds16(vBase + (size_t)d * (Mlen * 2) + kv0 * 2 + inner,
             (char*)(&Vlds[buf][0]) + (i * 4 + w) * 1024);
    }
  };

  auto STEP_HEAD = [&](int tile) {
    if (tile + 1 < NTT) {
      stageKV((tile + 1) & 3, tile + 1);
      asm volatile("s_waitcnt vmcnt(4)" ::: "memory");
    } else {
      asm volatile("s_waitcnt vmcnt(0)" ::: "memory");
    }
    __builtin_amdgcn_s_barrier();
    __builtin_amdgcn_sched_barrier(0);
  };
  auto QK = [&](int tile, f32x16& s0, f32x16& s1) {
    const char* kb_ = (const char*)(&Klds[tile & 3][0]);
    __builtin_amdgcn_s_setprio(1);
#pragma unroll
    for (int dks = 0; dks < 4; ++dks) {
      const int a0 = (0 * 32 + l31) * 128 + ((dks * 32 + hi * 16) ^ key);
      const int a1 = (1 * 32 + l31) * 128 + ((dks * 32 + hi * 16) ^ key);
      bf16x8 kf0 = *(const bf16x8*)(kb_ + a0);
      bf16x8 kf1 = *(const bf16x8*)(kb_ + a1);
      s0 = __builtin_amdgcn_mfma_f32_32x32x16_bf16(kf0, qf[dks], s0, 0, 0, 0);
      s1 = __builtin_amdgcn_mfma_f32_32x32x16_bf16(kf1, qf[dks], s1, 0, 0, 0);
    }
    __builtin_amdgcn_s_setprio(0);
  };
  auto EXP = [&](const f32x16& s0, const f32x16& s1, u32 (&w0)[8], u32 (&w1)[8]) {
#pragma unroll
    for (int e2 = 0; e2 < 8; ++e2) {
      const float p00 = __builtin_amdgcn_exp2f(s0[2 * e2]);
      const float p01 = __builtin_amdgcn_exp2f(s0[2 * e2 + 1]);
      const float p10 = __builtin_amdgcn_exp2f(s1[2 * e2]);
      const float p11 = __builtin_amdgcn_exp2f(s1[2 * e2 + 1]);
      bf16x2 k0; k0[0] = (bf16)p00; k0[1] = (bf16)p01;
      bf16x2 k1; k1[0] = (bf16)p10; k1[1] = (bf16)p11;
      w0[e2] = __builtin_bit_cast(u32, k0);
      w1[e2] = __builtin_bit_cast(u32, k1);
    }
  };
  auto PV = [&](int tprev, const u32 (&w0)[8], const u32 (&w1)[8]) {
    const char* vb_ = (const char*)(&Vlds[tprev & 3][0]);
    __builtin_amdgcn_s_setprio(1);
#pragma unroll
    for (int ks = 0; ks < 2; ++ks) {
      auto sa0 = __builtin_amdgcn_permlane32_swap(w0[4 * ks + 0], w0[4 * ks + 2], false, false);
      auto sa1 = __builtin_amdgcn_permlane32_swap(w0[4 * ks + 1], w0[4 * ks + 3], false, false);
      auto sb0 = __builtin_amdgcn_permlane32_swap(w1[4 * ks + 0], w1[4 * ks + 2], false, false);
      auto sb1 = __builtin_amdgcn_permlane32_swap(w1[4 * ks + 1], w1[4 * ks + 3], false, false);
      u32x4 fa, fb;
      fa[0] = (u32)sa0[0]; fa[1] = (u32)sa1[0]; fa[2] = (u32)sa0[1]; fa[3] = (u32)sa1[1];
      fb[0] = (u32)sb0[0]; fb[1] = (u32)sb1[0]; fb[2] = (u32)sb0[1]; fb[3] = (u32)sb1[1];
      const bf16x8 pa = __builtin_bit_cast(bf16x8, fa);
      const bf16x8 pb = __builtin_bit_cast(bf16x8, fb);
      const int c0 = (ks * 32 + hi * 16);
      bf16x8 va0 = *(const bf16x8*)(vb_ + (0 * 32 + l31) * 128 + ((0 * 64 + c0) ^ key));
      bf16x8 va1 = *(const bf16x8*)(vb_ + (1 * 32 + l31) * 128 + ((0 * 64 + c0) ^ key));
      bf16x8 vb0 = *(const bf16x8*)(vb_ + (0 * 32 + l31) * 128 + ((1 * 64 + c0) ^ key));
      bf16x8 vb1 = *(const bf16x8*)(vb_ + (1 * 32 + l31) * 128 + ((1 * 64 + c0) ^ key));
      acco0 = __builtin_amdgcn_mfma_f32_32x32x16_bf16(pa, va0, acco0, 0, 0, 0);
      acco1 = __builtin_amdgcn_mfma_f32_32x32x16_bf16(pa, va1, acco1, 0, 0, 0);
      accl  = __builtin_amdgcn_mfma_f32_32x32x16_bf16(pa, ones, accl, 0, 0, 0);
      acco0 = __builtin_amdgcn_mfma_f32_32x32x16_bf16(pb, vb0, acco0, 0, 0, 0);
      acco1 = __builtin_amdgcn_mfma_f32_32x32x16_bf16(pb, vb1, acco1, 0, 0, 0);
      accl  = __builtin_amdgcn_mfma_f32_32x32x16_bf16(pb, ones, accl, 0, 0, 0);
    }
    __builtin_amdgcn_s_setprio(0);
  };

  u32 wE0[8], wE1[8], wO0[8], wO1[8];
  f32x16 s0, s1;

  stageKV(0, 0);
  STEP_HEAD(0);
  s0 = f32x16{}; s1 = f32x16{};
  QK(0, s0, s1);
  EXP(s0, s1, wE0, wE1);
  for (int tp = 0; tp < 15; ++tp) {
    const int to = 2 * tp + 1;
    STEP_HEAD(to);
    s0 = f32x16{}; s1 = f32x16{};
    QK(to, s0, s1);
    PV(to - 1, wE0, wE1);
    EXP(s0, s1, wO0, wO1);
    const int te = to + 1;
    STEP_HEAD(te);
    s0 = f32x16{}; s1 = f32x16{};
    QK(te, s0, s1);
    PV(te - 1, wO0, wO1);
    EXP(s0, s1, wE0, wE1);
  }
  STEP_HEAD(31);
  s0 = f32x16{}; s1 = f32x16{};
  QK(31, s0, s1);
  PV(30, wE0, wE1);
  EXP(s0, s1, wO0, wO1);
  PV(31, wO0, wO1);

  const int b = bh >> 4, h = bh & 15;
#pragma unroll
  for (int e = 0; e < 16; ++e) {
    const int ql = (e & 3) + 8 * (e >> 2) + 4 * hi;
    const float iv = 1.0f / accl[e];
    const size_t row = (size_t)(b * 2048 + qr + ql) * 1024 + h * 64;
    Out[row + l31]      = (bf16)(acco0[e] * iv);
    Out[row + 32 + l31] = (bf16)(acco1[e] * iv);
  }
}

// ---------------- launch ----------------
extern "C" void kernel_launch(void* const* d_in, const int* in_sizes, int n_in,
                              void* d_out, int out_size, void* d_ws, size_t ws_size,
                              hipStream_t stream) {
  const float* q  = (const float*)d_in[0];
  const float* k  = (const float*)d_in[1];
  const float* v  = (const float*)d_in[2];
  const float* Wq = (const float*)d_in[3];
  const float* Wk = (const float*)d_in[4];
  const float* Wv = (const float*)d_in[5];
  const float* Wo = (const float*)d_in[6];

  char* ws = (char*)d_ws;
  const dim3 cb(256);

  if (ws_size >= ((size_t)56 << 20)) {
    // Wb@0(8M); Xq/Xk/Xv@8/16/24; qb/kb/vb@32/40/48; Xa@8 (reuse Xq)
    bf16* Wb = (bf16*)ws;
    bf16* Xq = (bf16*)(ws + (8u  << 20));
    bf16* Xk = (bf16*)(ws + (16u << 20));
    bf16* Xv = (bf16*)(ws + (24u << 20));
    bf16* qb = (bf16*)(ws + (32u << 20));
    bf16* kb = (bf16*)(ws + (40u << 20));
    bf16* vb = (bf16*)(ws + (48u << 20));
    bf16* Xa = (bf16*)(ws + (8u  << 20));

    cvt_all<<<8192, cb, 0, stream>>>(Wq, Wk, Wv, Wo, q, k, v, Wb, Xq);
    gemm_qkv<<<dim3(32, 8, 3), cb, 0, stream>>>(Xq, Xk, Xv, Wb, qb, kb, vb, 0);
    attn_fwd<<<512, cb, 0, stream>>>(qb, kb, vb, Xa);
    gemm_out<<<dim3(32, 16), cb, 0, stream>>>(Xa, Wb + 3 * (1u << 20), (float*)d_out);
  } else {
    // serial fallback (40MB): Wb@0, X@8 (shared), qb@16, kb@24, vb@32, Xa@8
    bf16* Wb = (bf16*)ws;
    bf16* X  = (bf16*)(ws + (8u  << 20));
    bf16* qb = (bf16*)(ws + (16u << 20));
    bf16* kb = (bf16*)(ws + (24u << 20));
    bf16* vb = (bf16*)(ws + (32u << 20));
    bf16* Xa = (bf16*)(ws + (8u  << 20));

    cvt_all<<<2048, cb, 0, stream>>>(Wq, Wk, Wv, Wo, q, k, v, Wb, Wb); // weights only
    cvt_bf16<<<2048, cb, 0, stream>>>(q, X, 524288);
    gemm_qkv<<<dim3(32, 8, 1), cb, 0, stream>>>(X, X, X, Wb, qb, kb, vb, 0);
    cvt_bf16<<<2048, cb, 0, stream>>>(k, X, 524288);
    gemm_qkv<<<dim3(32, 8, 1), cb, 0, stream>>>(X, X, X, Wb, qb, kb, vb, 1);
    cvt_bf16<<<2048, cb, 0, stream>>>(v, X, 524288);
    gemm_qkv<<<dim3(32, 8, 1), cb, 0, stream>>>(X, X, X, Wb, qb, kb, vb, 2);
    attn_fwd<<<512, cb, 0, stream>>>(qb, kb, vb, Xa);
    gemm_out<<<dim3(32, 16), cb, 0, stream>>>(Xa, Wb + 3 * (1u << 20), (float*)d_out);
  }
}